// Round 5
// baseline (343.238 us; speedup 1.0000x reference)
//
#include <hip/hip_runtime.h>

// VectorQuantizer forward: inputs [64,2048,64] f32, codebook [1024,64] f32.
// Outputs (f32, concat): quantized_ste [8388608], loss [1], indices-as-float [131072].
//
// Round 13: R9/R10/R12 fit busy = W*C/(C+S) with S ~ proportional to C ->
// the per-chunk stall is a fixed FRACTION of issue, i.e. the serialized-
// scalar-miss path: 16 s_load_dwordx4/chunk miss K$ (per-CU working set
// 256KB vs 16KB K$), scalar misses serialize (~160cy each, non-pipelined),
// and lgkmcnt(0) full-drain exposes them every chunk. W (2->4) and C
// (256->512) both failed to move VALUBusy past 67%. Fix: deliver B via the
// VECTOR memory path - drop readfirstlane on the codebook pointer so wid
// stays formally divergent -> compiler cannot scalarize -> per-lane
// global_load_dwordx4 (equal addrs, coalescer broadcast). VMEM misses
// pipeline (16 outstanding ~ L+eps), vmcnt waits are counted, and
// #pragma unroll 2 on the 4-dim chunk loop lets the compiler prefetch
// chunk k+1 under chunk k's FMAs. bb moves SGPR->VGPR: ~120 VGPR total,
// under the (512,4) 128-cap -> keeps 2 blocks/CU (W=4). csq stays scalar
// (4KB, K$-resident, hits cheap).
//
// Numerics: BIT-IDENTICAL to R12 - same load bits, same FMA order
// (k = 4*kc + k8 ascending 0..63), same fl(fl(asq-2*acc)+csq) tail, same
// ascending strict-less argmin + u64 cross-wave merge, same epilogue
// (tid<256, 4x 64-row units -> identical 2048 loss partials).

#define NROWS  131072
#define DIM    64
#define KCB    1024
#define MTB    256            // rows per block (staged once in LDS)
#define QSIZE  (NROWS * DIM)  // 8388608

typedef unsigned long long u64;

__global__ __launch_bounds__(256) void vq_prep(const float* __restrict__ cb,
                                               float* __restrict__ csq,
                                               float* __restrict__ loss_slot) {
    int k = blockIdx.x * 256 + threadIdx.x;
    if (k < KCB) {
        const float* c = cb + k * DIM;
        float a0 = 0.f, a1 = 0.f, a2 = 0.f, a3 = 0.f;
        #pragma unroll
        for (int d = 0; d < 16; ++d) {
            a0 = fmaf(c[d],      c[d],      a0);
            a1 = fmaf(c[16 + d], c[16 + d], a1);
            a2 = fmaf(c[32 + d], c[32 + d], a2);
            a3 = fmaf(c[48 + d], c[48 + d], a3);
        }
        csq[k] = (a0 + a1) + (a2 + a3);
    }
    if (blockIdx.x == 0 && threadIdx.x == 0) *loss_slot = 0.f;  // zero loss accumulator every call
}

__global__ __launch_bounds__(512, 4) void vq_main(const float* __restrict__ x,
                                                  const float* __restrict__ cb,
                                                  const float* __restrict__ csq,
                                                  float* __restrict__ out_q,
                                                  float* __restrict__ out_loss,
                                                  float* __restrict__ out_idx) {
    // 64 KB region: sA during GEMM; sWK/sFinal/sLoss after (all post-GEMM,
    // fenced by __syncthreads before first aliased write).
    __shared__ __align__(16) char smem[DIM * MTB * 4];
    float (*sA)[MTB] = reinterpret_cast<float (*)[MTB]>(smem);             // [64][256] f32
    u64   (*sWK)[MTB] = reinterpret_cast<u64 (*)[MTB]>(smem);              // [8][256] u64 = 16 KB
    int*   sFinal = reinterpret_cast<int*>(smem + 8 * MTB * 8);            // +16 KB, [256]
    float* sLoss  = reinterpret_cast<float*>(smem + 8 * MTB * 8 + MTB * 4);// +17 KB, [4]
    __shared__ __align__(16) float sPart[MTB][4];  // 4 KB, A-norm quarter chains (staging-live)
    __shared__ __align__(16) float sAn[MTB];       // 1 KB, A-norms (GEMM-live)
    // total ~70.7 KB -> 2 blocks/CU = 16 waves/CU = 4 waves/SIMD (if VGPR<=128)

    const int tid  = threadIdx.x;
    const int lane = tid & 63;
    const int wid  = tid >> 6;           // 0..7 (kept DIVERGENT for cbw)
    const size_t rowbase = (size_t)blockIdx.x * MTB;

    // ---- stage A (256 rows) dim-major + exact A-norm quarter chains ----
    {
        const int r = tid >> 1;      // 0..255
        const int h = tid & 1;       // dim half 32h..32h+31 (= quarters 2h, 2h+1)
        const float4* gx = reinterpret_cast<const float4*>(
            x + (rowbase + (size_t)r) * DIM + 32 * h);
        float4 v0 = gx[0], v1 = gx[1], v2 = gx[2], v3 = gx[3];
        float4 v4 = gx[4], v5 = gx[5], v6 = gx[6], v7 = gx[7];
        float t[32] = {v0.x, v0.y, v0.z, v0.w, v1.x, v1.y, v1.z, v1.w,
                       v2.x, v2.y, v2.z, v2.w, v3.x, v3.y, v3.z, v3.w,
                       v4.x, v4.y, v4.z, v4.w, v5.x, v5.y, v5.z, v5.w,
                       v6.x, v6.y, v6.z, v6.w, v7.x, v7.y, v7.z, v7.w};
        float aq0 = 0.f, aq1 = 0.f;
        #pragma unroll
        for (int j = 0; j < 16; ++j) aq0 = fmaf(t[j],      t[j],      aq0);  // chain 2h
        #pragma unroll
        for (int j = 0; j < 16; ++j) aq1 = fmaf(t[16 + j], t[16 + j], aq1);  // chain 2h+1
        sPart[r][2 * h]     = aq0;
        sPart[r][2 * h + 1] = aq1;
        #pragma unroll
        for (int j = 0; j < 32; ++j) sA[32 * h + j][r] = t[j];   // dim-major scatter
    }
    __syncthreads();
    if (tid < MTB)
        sAn[tid] = (sPart[tid][0] + sPart[tid][1]) + (sPart[tid][2] + sPart[tid][3]);
    __syncthreads();

    // ---- per-thread rows: r0..r0+3; per-wave codes: slice [wid*128, wid*128+128) ----
    const int r0 = 4 * lane;
    float asq[4];
    {
        const float4 an = *reinterpret_cast<const float4*>(&sAn[r0]);
        asq[0] = an.x; asq[1] = an.y; asq[2] = an.z; asq[3] = an.w;
    }
    // cbw: built from DIVERGENT wid -> compiler must use vector loads (VMEM,
    // pipelined, counted vmcnt waits). All 64 lanes carry the same address;
    // the coalescer broadcasts. This replaces the serialized K$-miss s_loads.
    const float* cbw = cb + (size_t)wid * 128 * DIM;
    // csw: uniform -> scalar loads (csq is 4KB, K$-resident, hits cheap).
    const int cu = __builtin_amdgcn_readfirstlane(wid);
    const float* csw = csq + cu * 128;

    float kd[4] = {__builtin_inff(), __builtin_inff(), __builtin_inff(), __builtin_inff()};
    int   ki[4] = {0, 0, 0, 0};

    #pragma unroll 1
    for (int g = 0; g < 16; ++g) {           // 8 codes per group
        const float* bp = cbw + (size_t)g * 8 * DIM;
        float acc[4][8];
        #pragma unroll
        for (int r = 0; r < 4; ++r)
            #pragma unroll
            for (int c = 0; c < 8; ++c) acc[r][c] = 0.f;

        #pragma unroll 2
        for (int kc = 0; kc < 16; ++kc) {    // 4 dims per chunk; unroll 2 -> prefetch
            const float* bkc = bp + 4 * kc;
            float4 bbv[8];                   // per-lane VGPRs (uniform values)
            #pragma unroll
            for (int c = 0; c < 8; ++c)
                bbv[c] = *reinterpret_cast<const float4*>(bkc + 64 * c);
            #pragma unroll
            for (int k8 = 0; k8 < 4; ++k8) { // sequential k-chain 0..63 preserved
                const float4 av = *reinterpret_cast<const float4*>(&sA[4 * kc + k8][r0]);
                #pragma unroll
                for (int c = 0; c < 8; ++c) {
                    const float bf = (k8 == 0) ? bbv[c].x :
                                     (k8 == 1) ? bbv[c].y :
                                     (k8 == 2) ? bbv[c].z : bbv[c].w;
                    acc[0][c] = fmaf(av.x, bf, acc[0][c]);
                    acc[1][c] = fmaf(av.y, bf, acc[1][c]);
                    acc[2][c] = fmaf(av.z, bf, acc[2][c]);
                    acc[3][c] = fmaf(av.w, bf, acc[3][c]);
                }
            }
        }

        // ---- tail: d2 + argmin update (ref expression roundings preserved) ----
        const float4 cs0 = *reinterpret_cast<const float4*>(csw + 8 * g);
        const float4 cs1 = *reinterpret_cast<const float4*>(csw + 8 * g + 4);
        const float css[8] = {cs0.x, cs0.y, cs0.z, cs0.w, cs1.x, cs1.y, cs1.z, cs1.w};
        const int nb = (cu << 7) + (g << 3);
        #pragma unroll
        for (int c = 0; c < 8; ++c) {
            const float cs = css[c];
            const int n = nb + c;
            #pragma unroll
            for (int r = 0; r < 4; ++r) {
                const float tt = asq[r] - 2.0f * acc[r][c];  // one rounding (2*acc exact)
                const float dd = tt + cs;                    // second rounding
                const bool lt = dd < kd[r];                  // strict-less: first-index-wins
                kd[r] = lt ? dd : kd[r];
                ki[r] = lt ? n  : ki[r];
            }
        }
    }

    // ---- cross-wave argmin merge (u64 keys, order-free, first-index-wins) ----
    __syncthreads();                         // all sA reads done -> safe to alias sWK
    #pragma unroll
    for (int i = 0; i < 4; ++i)
        sWK[wid][r0 + i] =
            ((u64)__float_as_uint(kd[i]) << 32) | (unsigned)ki[i];
    __syncthreads();
    if (tid < MTB) {
        u64 m = sWK[0][tid];
        #pragma unroll
        for (int w = 1; w < 8; ++w) {
            const u64 b = sWK[w][tid];
            m = b < m ? b : m;               // u64 min: associative/commutative
        }
        const int idx = (int)(unsigned)m;
        sFinal[tid] = idx;
        out_idx[rowbase + tid] = (float)idx;
    }
    __syncthreads();

    // ---- epilogue: round-9 verbatim (tid<256, 4x 64-row units, identical partials) ----
    #pragma unroll 1
    for (int sub = 0; sub < 4; ++sub) {
        if (tid < 256) {
            const size_t base = (rowbase + 64 * sub) * DIM;
            float lsum = 0.f;
            #pragma unroll 4
            for (int i = tid; i < 64 * DIM; i += 256) {
                const int r = i >> 6;
                const int d = i & 63;
                const int kb = sFinal[64 * sub + r];   // wave-uniform per iteration
                const float q  = cb[(size_t)kb * DIM + d];
                const float xe = x[base + i];
                out_q[base + i] = xe + (q - xe);        // STE forward, ref's rounding
                const float df = q - xe;
                lsum = fmaf(df, df, lsum);
            }
            #pragma unroll
            for (int off = 32; off; off >>= 1) lsum += __shfl_down(lsum, off, 64);
            if (lane == 0) sLoss[wid] = lsum;
        }
        __syncthreads();
        if (tid == 0) {
            const float tot = (sLoss[0] + sLoss[1]) + (sLoss[2] + sLoss[3]);
            atomicAdd(out_loss, tot * (1.25f / 8388608.0f));  // (q + 0.25*e) / count
        }
        __syncthreads();
    }
}

extern "C" void kernel_launch(void* const* d_in, const int* in_sizes, int n_in,
                              void* d_out, int out_size, void* d_ws, size_t ws_size,
                              hipStream_t stream) {
    const float* x  = (const float*)d_in[0];   // 8388608
    const float* cb = (const float*)d_in[1];   // 65536
    float* out      = (float*)d_out;
    float* out_loss = out + QSIZE;             // [8388608]
    float* out_idx  = out + QSIZE + 1;         // [8388609 .. 8519680]
    float* csq      = (float*)d_ws;            // 1024 floats scratch

    vq_prep<<<4, 256, 0, stream>>>(cb, csq, out_loss);
    vq_main<<<NROWS / MTB, 512, 0, stream>>>(x, cb, csq, out, out_loss, out_idx);
}

// Round 6
// 232.887 us; speedup vs baseline: 1.4738x; 1.4738x over previous
//
#include <hip/hip_runtime.h>

// VectorQuantizer forward: inputs [64,2048,64] f32, codebook [1024,64] f32.
// Outputs (f32, concat): quantized_ste [8388608], loss [1], indices-as-float [131072].
//
// Round 14: MFMA rewrite. R9-R13 proved every B-delivery path for the
// FMA-vector structure stalls (SMEM serialized K$ misses, VMEM broadcast,
// LDS broadcast) and the pure-VALU floor is ~150us anyway. Outputs only need
// the argmin INDEX, so: bf16 hi/lo split (3-term products, exact bf16x bf16
// ->f32) on mfma_f32_16x16x32_bf16 gives dot with |err| <= ~2e-6; argmin
// filter runs on m = cs - 2*dot (asq cancels) quantized to a u32 key
// (m*2^18 + bias)<<10 | idx -> top-3 per row via 5x v_min/max_u32.
// Rows where gap12 exceeds an asq-scaled safe margin (ulp-derived; ~99%)
// take min1; hot rows recompute EXACT d2 (bit-identical R12 chain:
// sequential fmaf k=0..63, fl(fl(asq-2acc)+cs), u64 first-index-wins) for
// the <=3 in-margin candidates. K-order inside MFMA fragments cancels
// between A and B (same per-lane load pattern); C/D layout is the
// HW-verified col=lane&15, row=(lane>>4)*4+reg.
// Loss/STE epilogue: identical 64-row units as all prior rounds
// (2048 identical partials, atomicAdd-accumulated).

#define NROWS  131072
#define DIM    64
#define KCB    1024
#define QSIZE  (NROWS * DIM)  // 8388608

typedef unsigned long long u64;
typedef unsigned int u32;
typedef unsigned short ushortx;
typedef __attribute__((ext_vector_type(8))) short short8v;
typedef __attribute__((ext_vector_type(4))) float f32x4;

__device__ __forceinline__ u32 umin32(u32 a, u32 b) { return a < b ? a : b; }
__device__ __forceinline__ u32 umax32(u32 a, u32 b) { return a > b ? a : b; }

// RNE f32 -> bf16 (deterministic, internal-only precision split)
__device__ __forceinline__ ushortx f2bf(float f) {
    u32 u = __float_as_uint(f);
    u32 r = u + 0x7FFFu + ((u >> 16) & 1u);
    return (ushortx)(r >> 16);
}
__device__ __forceinline__ float bf2f(ushortx h) {
    return __uint_as_float(((u32)h) << 16);
}

// ---- prep: csq (exact quarter chains, as all prior rounds), cs18b key bias,
// ---- bf16 hi/lo codebook split, and loss-slot zeroing ----
__global__ __launch_bounds__(256) void vq_prep(const float* __restrict__ cb,
                                               float* __restrict__ csq,
                                               float* __restrict__ cs18b,
                                               ushortx* __restrict__ cbh,
                                               ushortx* __restrict__ cbl,
                                               float* __restrict__ loss_slot) {
    int k = blockIdx.x * 256 + threadIdx.x;
    if (k < KCB) {
        const float* c = cb + k * DIM;
        float a0 = 0.f, a1 = 0.f, a2 = 0.f, a3 = 0.f;
        #pragma unroll
        for (int d = 0; d < 16; ++d) {
            a0 = fmaf(c[d],      c[d],      a0);
            a1 = fmaf(c[16 + d], c[16 + d], a1);
            a2 = fmaf(c[32 + d], c[32 + d], a2);
            a3 = fmaf(c[48 + d], c[48 + d], a3);
        }
        const float cs = (a0 + a1) + (a2 + a3);
        csq[k] = cs;
        cs18b[k] = cs * 262144.0f + 131072.0f;   // m*2^18 + bias stays in [0,2^18)
        #pragma unroll 4
        for (int d = 0; d < DIM; ++d) {
            const float f = c[d];
            const ushortx h = f2bf(f);
            cbh[k * DIM + d] = h;
            cbl[k * DIM + d] = f2bf(f - bf2f(h));
        }
    }
    if (blockIdx.x == 0 && threadIdx.x == 0) *loss_slot = 0.f;
}

// ---- main: 256 threads = 4 waves; block = 128 rows (wave owns 32 rows,
// ---- sweeps all 1024 codes; no cross-wave argmin merge needed) ----
__global__ __launch_bounds__(256, 4) void vq_main(const float* __restrict__ x,
                                                  const float* __restrict__ cb,
                                                  const float* __restrict__ csq,
                                                  const float* __restrict__ cs18b,
                                                  const ushortx* __restrict__ cbh,
                                                  const ushortx* __restrict__ cbl,
                                                  float* __restrict__ out_q,
                                                  float* __restrict__ out_loss,
                                                  float* __restrict__ out_idx) {
    __shared__ u32   sTop[4][32][3];
    __shared__ int   sFinal[128];
    __shared__ float sLoss[4];

    const int tid  = threadIdx.x;
    const int lane = tid & 63;
    const int wid  = tid >> 6;            // 0..3
    const size_t rowbase = (size_t)blockIdx.x * 128;
    const int wrow0 = wid * 32;           // block-local first row of this wave
    const int lcol  = lane & 15;          // A-row-in-tile / B-col / D-col
    const int lkq   = lane >> 4;          // k-chunk 0..3

    // ---- A fragments: 2 rowtiles x 2 k-halves, hi/lo bf16 splits ----
    short8v Ah[2][2], Al[2][2];
    #pragma unroll
    for (int t = 0; t < 2; ++t)
        #pragma unroll
        for (int h = 0; h < 2; ++h) {
            const float* xp = x + (rowbase + (size_t)(wrow0 + t * 16 + lcol)) * DIM
                              + h * 32 + lkq * 8;
            const float4 u0 = *reinterpret_cast<const float4*>(xp);
            const float4 u1 = *reinterpret_cast<const float4*>(xp + 4);
            const float xv[8] = {u0.x, u0.y, u0.z, u0.w, u1.x, u1.y, u1.z, u1.w};
            union { ushortx u[8]; short8v v; } uh, ul;
            #pragma unroll
            for (int j = 0; j < 8; ++j) {
                const ushortx hh = f2bf(xv[j]);
                uh.u[j] = hh;
                ul.u[j] = f2bf(xv[j] - bf2f(hh));
            }
            Ah[t][h] = uh.v;
            Al[t][h] = ul.v;
        }

    // ---- code sweep: top-3 u32 keys per row-slot (8 slots/lane) ----
    u32 k1[8], k2[8], k3[8];
    #pragma unroll
    for (int s = 0; s < 8; ++s) { k1[s] = ~0u; k2[s] = ~0u; k3[s] = ~0u; }

    u32 nlane = (u32)lcol;
    const ushortx* bhp = cbh + (size_t)lcol * DIM + lkq * 8;
    const ushortx* blp = cbl + (size_t)lcol * DIM + lkq * 8;

    #pragma unroll 1
    for (int ct = 0; ct < 64; ++ct) {     // 16 codes per tile
        const short8v Bh0 = *reinterpret_cast<const short8v*>(bhp);
        const short8v Bh1 = *reinterpret_cast<const short8v*>(bhp + 32);
        const short8v Bl0 = *reinterpret_cast<const short8v*>(blp);
        const short8v Bl1 = *reinterpret_cast<const short8v*>(blp + 32);
        const float csb = cs18b[nlane];
        #pragma unroll
        for (int t = 0; t < 2; ++t) {
            f32x4 acc = (f32x4){0.f, 0.f, 0.f, 0.f};
            acc = __builtin_amdgcn_mfma_f32_16x16x32_bf16(Ah[t][0], Bh0, acc, 0, 0, 0);
            acc = __builtin_amdgcn_mfma_f32_16x16x32_bf16(Al[t][0], Bh0, acc, 0, 0, 0);
            acc = __builtin_amdgcn_mfma_f32_16x16x32_bf16(Ah[t][0], Bl0, acc, 0, 0, 0);
            acc = __builtin_amdgcn_mfma_f32_16x16x32_bf16(Ah[t][1], Bh1, acc, 0, 0, 0);
            acc = __builtin_amdgcn_mfma_f32_16x16x32_bf16(Al[t][1], Bh1, acc, 0, 0, 0);
            acc = __builtin_amdgcn_mfma_f32_16x16x32_bf16(Ah[t][1], Bl1, acc, 0, 0, 0);
            #pragma unroll
            for (int r = 0; r < 4; ++r) {
                const float m18 = fmaf(acc[r], -524288.0f, csb);  // (cs-2dot)*2^18+bias
                const u32 key = ((u32)m18 << 10) | nlane;          // trunc-cvt, monotone
                const int s = t * 4 + r;
                const u32 nk1 = umin32(key, k1[s]);
                const u32 mx  = umax32(key, k1[s]);
                const u32 nk2 = umin32(k2[s], mx);
                const u32 mx2 = umax32(k2[s], mx);
                k3[s] = umin32(k3[s], mx2);
                k1[s] = nk1; k2[s] = nk2;
            }
        }
        bhp += 16 * DIM; blp += 16 * DIM; nlane += 16;
    }

    // ---- merge the 16 col-classes per row (butterfly over lanes 16g..16g+15) ----
    #pragma unroll
    for (int s = 0; s < 8; ++s) {
        u32 a1 = k1[s], a2 = k2[s], a3 = k3[s];
        #pragma unroll
        for (int mask = 1; mask <= 8; mask <<= 1) {
            const u32 b1 = __shfl_xor(a1, mask, 64);
            const u32 b2 = __shfl_xor(a2, mask, 64);
            const u32 b3 = __shfl_xor(a3, mask, 64);
            const u32 c1 = umin32(a1, b1), d1 = umax32(a1, b1);
            const u32 c2 = umin32(a2, b2);
            const u32 o3 = umin32(umax32(d1, c2), umin32(a3, b3));
            a1 = c1; a2 = umin32(d1, c2); a3 = o3;
        }
        k1[s] = a1; k2[s] = a2; k3[s] = a3;
    }
    if (lcol < 8) {   // lane 16g+j writes slot j -> row (j>>2)*16 + g*4 + (j&3)
        const int j = lcol, g = lkq;
        const int row = (j >> 2) * 16 + g * 4 + (j & 3);
        sTop[wid][row][0] = k1[j]; sTop[wid][row][1] = k2[j]; sTop[wid][row][2] = k3[j];
    }
    __syncthreads();

    // ---- per-row final: non-hot -> min1; hot -> exact d2 (R12 chain) on candidates ----
    if (lane < 32) {
        const int row = wrow0 + lane;                  // block-local 0..127
        const u32 K1 = sTop[wid][lane][0];
        const u32 K2 = sTop[wid][lane][1];
        const u32 K3 = sTop[wid][lane][2];
        int idx = (int)(K1 & 1023u);
        const u32 m1q = K1 >> 10, m2q = K2 >> 10, m3q = K3 >> 10;
        if (m2q - m1q <= 26u) {                        // coarse hot (covers asq<=166)
            const float* xr = x + (rowbase + (size_t)row) * DIM;
            float4 xv[16];
            #pragma unroll
            for (int q = 0; q < 16; ++q) xv[q] = reinterpret_cast<const float4*>(xr)[q];
            float p[4];
            #pragma unroll
            for (int q = 0; q < 4; ++q) {              // exact quarter chains
                float a = 0.f;
                #pragma unroll
                for (int e = 0; e < 4; ++e) {
                    const float4 v = xv[4 * q + e];
                    a = fmaf(v.x, v.x, a); a = fmaf(v.y, v.y, a);
                    a = fmaf(v.z, v.z, a); a = fmaf(v.w, v.w, a);
                }
                p[q] = a;
            }
            const float asq = (p[0] + p[1]) + (p[2] + p[3]);
            const u32 Mq = (u32)fmaf(asq, 0.126f, 5.0f);   // safe ulp-derived margin
            u64 best = ~0ull;
            #pragma unroll 1
            for (int c = 0; c < 3; ++c) {
                const u32 Kc = c == 0 ? K1 : (c == 1 ? K2 : K3);
                const u32 mq = Kc >> 10;
                if (c > 0 && (mq - m1q) > Mq) break;   // keys sorted: later ones farther
                const int n = (int)(Kc & 1023u);
                const float4* cr = reinterpret_cast<const float4*>(cb + (size_t)n * DIM);
                float acc = 0.f;
                #pragma unroll
                for (int q = 0; q < 16; ++q) {         // exact sequential k-chain 0..63
                    const float4 c4 = cr[q], v = xv[q];
                    acc = fmaf(v.x, c4.x, acc); acc = fmaf(v.y, c4.y, acc);
                    acc = fmaf(v.z, c4.z, acc); acc = fmaf(v.w, c4.w, acc);
                }
                const float tt = asq - 2.0f * acc;     // ref rounding 1
                const float dd = tt + csq[n];          // ref rounding 2
                const u64 kk = ((u64)__float_as_uint(dd) << 32) | (u32)n;
                best = kk < best ? kk : best;
            }
            idx = (int)(u32)best;
        }
        sFinal[row] = idx;
        out_idx[rowbase + row] = (float)idx;
    }
    __syncthreads();

    // ---- epilogue: STE + loss in the identical 64-row units (2 per block) ----
    #pragma unroll 1
    for (int sub = 0; sub < 2; ++sub) {
        const size_t base = (rowbase + 64 * sub) * DIM;
        float lsum = 0.f;
        #pragma unroll 4
        for (int i = tid; i < 64 * DIM; i += 256) {
            const int r = i >> 6;
            const int d = i & 63;
            const int kb = sFinal[64 * sub + r];
            const float q  = cb[(size_t)kb * DIM + d];
            const float xe = x[base + i];
            out_q[base + i] = xe + (q - xe);            // STE forward, ref's rounding
            const float df = q - xe;
            lsum = fmaf(df, df, lsum);
        }
        #pragma unroll
        for (int off = 32; off; off >>= 1) lsum += __shfl_down(lsum, off, 64);
        if (lane == 0) sLoss[wid] = lsum;
        __syncthreads();
        if (tid == 0) {
            const float tot = (sLoss[0] + sLoss[1]) + (sLoss[2] + sLoss[3]);
            atomicAdd(out_loss, tot * (1.25f / 8388608.0f));
        }
        __syncthreads();
    }
}

extern "C" void kernel_launch(void* const* d_in, const int* in_sizes, int n_in,
                              void* d_out, int out_size, void* d_ws, size_t ws_size,
                              hipStream_t stream) {
    const float* x  = (const float*)d_in[0];   // 8388608
    const float* cb = (const float*)d_in[1];   // 65536
    float* out      = (float*)d_out;
    float* out_loss = out + QSIZE;             // [8388608]
    float* out_idx  = out + QSIZE + 1;         // [8388609 .. 8519680]

    float*   csq   = (float*)d_ws;             // 1024 f32
    float*   cs18b = csq + 1024;               // 1024 f32
    ushortx* cbh   = (ushortx*)(csq + 2048);   // 1024*64 bf16-hi (128 KB)
    ushortx* cbl   = cbh + KCB * DIM;          // 1024*64 bf16-lo (128 KB)

    vq_prep<<<4, 256, 0, stream>>>(cb, csq, cs18b, cbh, cbl, out_loss);
    vq_main<<<NROWS / 128, 256, 0, stream>>>(x, cb, csq, cs18b, cbh, cbl,
                                             out, out_loss, out_idx);
}